// Round 1
// baseline (518.908 us; speedup 1.0000x reference)
//
#include <hip/hip_runtime.h>
#include <hip/hip_bf16.h>

typedef unsigned short ushort_t;
typedef unsigned int uint_t;
typedef __bf16 bf16x8 __attribute__((ext_vector_type(8)));
typedef float f32x4 __attribute__((ext_vector_type(4)));

#define B_SZ 32
#define C_IN 256
#define C_OUT 256
#define H_SZ 56
#define W_SZ 56
#define HW 3136          // 56*56
#define NP 100352        // B*HW
#define BN_EPS 1e-5f
#define K_ZERO 128       // channels zeroed per row

__device__ __forceinline__ ushort_t f2bf(float f) {
    unsigned int u = __builtin_bit_cast(unsigned int, f);
    unsigned int r = (u + 0x7fffu + ((u >> 16) & 1u)) >> 16;
    return (ushort_t)r;
}

// ---------------------------------------------------------------------------
// Kernel 1: x NCHW fp32 -> NHWC bf16  (so im2col K (=ci) is contiguous)
// grid: (4 ci-tiles, 56 h, 32 b), block 256
// ---------------------------------------------------------------------------
__global__ __launch_bounds__(256) void prep_x_kernel(const float* __restrict__ x,
                                                     ushort_t* __restrict__ xb) {
    const int cit = blockIdx.x, h = blockIdx.y, b = blockIdx.z;
    __shared__ float tile[64][57];  // +1 pad breaks transpose-read conflicts
    const int t = threadIdx.x;
    const float* src = x + ((size_t)(b * C_IN + cit * 64) * H_SZ + h) * W_SZ;
    for (int i = t; i < 64 * W_SZ; i += 256) {
        int ci = i / W_SZ, w = i - ci * W_SZ;
        tile[ci][w] = src[(size_t)ci * HW + w];
    }
    __syncthreads();
    // write: 2 ci per thread -> 4B stores, coalesced along ci
    for (int i = t; i < W_SZ * 32; i += 256) {
        int w = i >> 5, c2 = (i & 31) * 2;
        uint_t v = (uint_t)f2bf(tile[c2][w]) | ((uint_t)f2bf(tile[c2 + 1][w]) << 16);
        *(uint_t*)&xb[((size_t)((b * H_SZ + h) * W_SZ + w)) * C_IN + cit * 64 + c2] = v;
    }
}

// ---------------------------------------------------------------------------
// Kernel 2: weights OIHW fp32 -> Wt[tap][co][ci] bf16; + BN constants
// grid: 2304 blocks, 256
// ---------------------------------------------------------------------------
__global__ __launch_bounds__(256) void prep_w_kernel(const float* __restrict__ w,
                                                     const float* __restrict__ gamma,
                                                     const float* __restrict__ beta,
                                                     const float* __restrict__ mean,
                                                     const float* __restrict__ var,
                                                     ushort_t* __restrict__ Wt,
                                                     float* __restrict__ bninv,
                                                     float* __restrict__ bnadd) {
    int idx = blockIdx.x * 256 + threadIdx.x;
    if (idx < 9 * C_OUT * C_IN) {
        int tap = idx >> 16;        // /65536
        int rem = idx & 65535;
        int co = rem >> 8, ci = rem & 255;
        Wt[idx] = f2bf(w[(size_t)(co * C_IN + ci) * 9 + tap]);
    }
    if (blockIdx.x == 0 && threadIdx.x < C_OUT) {
        int c = threadIdx.x;
        float inv = gamma[c] * rsqrtf(var[c] + BN_EPS);
        bninv[c] = inv;
        bnadd[c] = beta[c] - mean[c] * inv;
    }
}

// ---------------------------------------------------------------------------
// Kernel 3: s[b][ci] = mean |x[b,ci,:,:]|   grid: 8192 blocks, 256
// ---------------------------------------------------------------------------
__global__ __launch_bounds__(256) void absmean_kernel(const float* __restrict__ x,
                                                      float* __restrict__ s) {
    const int bid = blockIdx.x;  // b*256 + ci
    const float4* p = (const float4*)(x + (size_t)bid * HW);
    float acc = 0.f;
    for (int i = threadIdx.x; i < HW / 4; i += 256) {
        float4 v = p[i];
        acc += fabsf(v.x) + fabsf(v.y) + fabsf(v.z) + fabsf(v.w);
    }
    for (int off = 32; off > 0; off >>= 1) acc += __shfl_down(acc, off, 64);
    __shared__ float wsum[4];
    if ((threadIdx.x & 63) == 0) wsum[threadIdx.x >> 6] = acc;
    __syncthreads();
    if (threadIdx.x == 0)
        s[bid] = (wsum[0] + wsum[1] + wsum[2] + wsum[3]) * (1.0f / (float)HW);
}

// ---------------------------------------------------------------------------
// Kernel 4: gate = relu(s @ gw^T + gb); zero K smallest (tie: lower index),
// renormalize *C_OUT/sum -> tscale[b][co].   grid: 32 blocks, 256
// ---------------------------------------------------------------------------
__global__ __launch_bounds__(256) void gate_kernel(const float* __restrict__ s,
                                                   const float* __restrict__ gw,
                                                   const float* __restrict__ gb,
                                                   float* __restrict__ tscale) {
    const int b = blockIdx.x, t = threadIdx.x;
    __shared__ float sh_s[C_IN], sh_g[C_OUT], red[256];
    sh_s[t] = s[b * C_IN + t];
    __syncthreads();
    float acc = gb[t];
    const float* wr = gw + (size_t)t * C_IN;
    for (int ci = 0; ci < C_IN; ci++) acc += sh_s[ci] * wr[ci];
    float g = fmaxf(acc, 0.f);
    sh_g[t] = g;
    __syncthreads();
    // rank (ascending value, ties -> lower index): rank < K_ZERO gets zeroed.
    int cnt = 0;
    for (int j = 0; j < C_OUT; j++) {
        float gj = sh_g[j];
        cnt += (gj < g) || (gj == g && j < t);
    }
    float tv = (cnt >= K_ZERO) ? g : 0.f;
    red[t] = tv;
    __syncthreads();
    for (int off = 128; off > 0; off >>= 1) {
        if (t < off) red[t] += red[t + off];
        __syncthreads();
    }
    tscale[b * C_OUT + t] = tv * ((float)C_OUT / red[0]);
}

// ---------------------------------------------------------------------------
// Kernel 5: implicit-GEMM conv + BN + ReLU + channel scale
// C[p][co] = sum_k Xcol[p][k] * W[k][co],  k = (tap, ci), K = 9*256 = 2304
// tile 128(p) x 128(co), BK=32 (one tap, 32 ci -> per-step-uniform validity)
// grid: (784, 2), block 256 (4 waves, each 64x64 via 4x4 16x16x32 MFMAs)
// ---------------------------------------------------------------------------
__global__ __launch_bounds__(256) void conv_kernel(const ushort_t* __restrict__ xb,
                                                   const ushort_t* __restrict__ Wt,
                                                   const float* __restrict__ bninv,
                                                   const float* __restrict__ bnadd,
                                                   const float* __restrict__ tscale,
                                                   float* __restrict__ out) {
    __shared__ __align__(16) ushort_t As[128 * 32];
    __shared__ __align__(16) ushort_t Bs[128 * 32];
    const int t = threadIdx.x;
    const int bx = blockIdx.x;  // p tile (784)
    const int by = blockIdx.y;  // co tile (2)
    const int lane = t & 63;
    const int wv = t >> 6;
    const int waveM = wv >> 1, waveN = wv & 1;

    // staging assignment: thread covers pixel rows (t>>2) and (t>>2)+64,
    // ci quad (t&3)*8 -> LDS writes are exactly t*16B: sequential, conflict-free
    const int pq = t >> 2;
    const int cq = (t & 3) * 8;
    int h_[2], w_[2], gb_[2], wb_[2];
#pragma unroll
    for (int pass = 0; pass < 2; pass++) {
        int p = bx * 128 + pq + pass * 64;
        int b = p / HW;
        int r = p - b * HW;
        int hh = r / W_SZ;
        int ww = r - hh * W_SZ;
        h_[pass] = hh;
        w_[pass] = ww;
        gb_[pass] = ((b * H_SZ + hh) * W_SZ + ww) * C_IN + cq;
        wb_[pass] = (by * 128 + pq + pass * 64) * C_IN + cq;
    }

    f32x4 acc[4][4];
#pragma unroll
    for (int i = 0; i < 4; i++)
#pragma unroll
        for (int j = 0; j < 4; j++) acc[i][j] = (f32x4){0.f, 0.f, 0.f, 0.f};

    for (int kk = 0; kk < 72; kk++) {
        const int tap = kk >> 3;
        const int ci0 = (kk & 7) << 5;
        const int dh = tap / 3 - 1, dw = tap - (tap / 3) * 3 - 1;
        const int doff = (dh * W_SZ + dw) * C_IN + ci0;
        const int woff = tap * 65536 + ci0;
#pragma unroll
        for (int pass = 0; pass < 2; pass++) {
            uint4 va = make_uint4(0u, 0u, 0u, 0u);
            int ih = h_[pass] + dh, iw = w_[pass] + dw;
            if ((unsigned)ih < (unsigned)H_SZ && (unsigned)iw < (unsigned)W_SZ)
                va = *(const uint4*)(xb + gb_[pass] + doff);
            *(uint4*)&As[(pq + pass * 64) * 32 + cq] = va;
            uint4 vb = *(const uint4*)(Wt + wb_[pass] + woff);
            *(uint4*)&Bs[(pq + pass * 64) * 32 + cq] = vb;
        }
        __syncthreads();
        bf16x8 af[4], bfr[4];
#pragma unroll
        for (int mt = 0; mt < 4; mt++)
            af[mt] = *(const bf16x8*)&As[(waveM * 64 + mt * 16 + (lane & 15)) * 32 + (lane >> 4) * 8];
#pragma unroll
        for (int nt = 0; nt < 4; nt++)
            bfr[nt] = *(const bf16x8*)&Bs[(waveN * 64 + nt * 16 + (lane & 15)) * 32 + (lane >> 4) * 8];
#pragma unroll
        for (int mt = 0; mt < 4; mt++)
#pragma unroll
            for (int nt = 0; nt < 4; nt++)
                acc[mt][nt] = __builtin_amdgcn_mfma_f32_16x16x32_bf16(af[mt], bfr[nt], acc[mt][nt], 0, 0, 0);
        __syncthreads();
    }

    // epilogue: y = relu(acc*inv + add) * tscale[b][co]; out is NCHW fp32.
    // acc element r: p = p0 + r (same co) -> float4 along p; 3136%4==0 so a
    // p-quad never crosses a batch boundary and stores are 16B-aligned.
#pragma unroll
    for (int mt = 0; mt < 4; mt++) {
        int p0 = bx * 128 + waveM * 64 + mt * 16 + (lane >> 4) * 4;
        int b = p0 / HW;
        int hw = p0 - b * HW;
#pragma unroll
        for (int nt = 0; nt < 4; nt++) {
            int co = by * 128 + waveN * 64 + nt * 16 + (lane & 15);
            float inv = bninv[co], add = bnadd[co], tsc = tscale[b * C_OUT + co];
            float4 o;
            o.x = fmaxf(acc[mt][nt][0] * inv + add, 0.f) * tsc;
            o.y = fmaxf(acc[mt][nt][1] * inv + add, 0.f) * tsc;
            o.z = fmaxf(acc[mt][nt][2] * inv + add, 0.f) * tsc;
            o.w = fmaxf(acc[mt][nt][3] * inv + add, 0.f) * tsc;
            *(float4*)(out + (size_t)(b * C_OUT + co) * HW + hw) = o;
        }
    }
}

// ---------------------------------------------------------------------------
extern "C" void kernel_launch(void* const* d_in, const int* in_sizes, int n_in,
                              void* d_out, int out_size, void* d_ws, size_t ws_size,
                              hipStream_t stream) {
    const float* x      = (const float*)d_in[0];
    const float* conv_w = (const float*)d_in[1];
    const float* gate_w = (const float*)d_in[2];
    const float* gate_b = (const float*)d_in[3];
    const float* bn_g   = (const float*)d_in[4];
    const float* bn_b   = (const float*)d_in[5];
    const float* bn_m   = (const float*)d_in[6];
    const float* bn_v   = (const float*)d_in[7];
    float* out = (float*)d_out;

    // workspace layout (needs ~52.7 MB)
    char* ws = (char*)d_ws;
    float*    s      = (float*)(ws + 0);         // 8192 f
    float*    tscale = (float*)(ws + 32768);     // 8192 f
    float*    bninv  = (float*)(ws + 65536);     // 256 f
    float*    bnadd  = (float*)(ws + 66560);     // 256 f
    ushort_t* Wt     = (ushort_t*)(ws + 67584);  // 589824 bf16
    ushort_t* xb     = (ushort_t*)(ws + 1247232);// 25690112 bf16

    prep_x_kernel<<<dim3(4, 56, 32), 256, 0, stream>>>(x, xb);
    prep_w_kernel<<<2304, 256, 0, stream>>>(conv_w, bn_g, bn_b, bn_m, bn_v, Wt, bninv, bnadd);
    absmean_kernel<<<8192, 256, 0, stream>>>(x, s);
    gate_kernel<<<32, 256, 0, stream>>>(s, gate_w, gate_b, tscale);
    conv_kernel<<<dim3(784, 2), 256, 0, stream>>>(xb, Wt, bninv, bnadd, tscale, out);
}

// Round 2
// 385.216 us; speedup vs baseline: 1.3471x; 1.3471x over previous
//
#include <hip/hip_runtime.h>
#include <hip/hip_bf16.h>
#include <cstdint>

typedef unsigned short ushort_t;
typedef unsigned int uint_t;
typedef __bf16 bf16x8 __attribute__((ext_vector_type(8)));
typedef float f32x4 __attribute__((ext_vector_type(4)));

#define B_SZ 32
#define C_IN 256
#define C_OUT 256
#define H_SZ 56
#define W_SZ 56
#define HW 3136          // 56*56
#define HP 58            // padded H (halo 1 each side)
#define WP 58            // padded W
#define BN_EPS 1e-5f
#define K_ZERO 128

__device__ __forceinline__ ushort_t f2bf(float f) {
    unsigned int u = __builtin_bit_cast(unsigned int, f);
    unsigned int r = (u + 0x7fffu + ((u >> 16) & 1u)) >> 16;
    return (ushort_t)r;
}

// async global->LDS, 16B per lane. LDS dest must be wave-uniform base + lane*16
// (it is: dest = base + t*16). Global address is per-lane (gather).
__device__ __forceinline__ void load_lds16(const void* gptr, void* ldsptr) {
    __builtin_amdgcn_global_load_lds(
        (const __attribute__((address_space(1))) unsigned int*)(uintptr_t)gptr,
        (__attribute__((address_space(3))) unsigned int*)(uintptr_t)ldsptr,
        16, 0, 0);
}

// ---------------------------------------------------------------------------
// Kernel 1: x NCHW fp32 -> padded NHWC bf16 (halo pre-zeroed by memset),
// fused abs-mean partial reduction (one atomicAdd per (b,ci) per block).
// grid: (4 ci-tiles, 56 h, 32 b), block 256
// ---------------------------------------------------------------------------
__global__ __launch_bounds__(256) void prep_x_kernel(const float* __restrict__ x,
                                                     ushort_t* __restrict__ xbp,
                                                     float* __restrict__ s) {
    const int cit = blockIdx.x, h = blockIdx.y, b = blockIdx.z;
    __shared__ float tile[64][57];  // +1 pad breaks transpose-read conflicts
    __shared__ float red2[256];
    const int t = threadIdx.x;
    const float* src = x + ((size_t)(b * C_IN + cit * 64) * H_SZ + h) * W_SZ;
    // read 64 ci-rows x 56 w as float4 (14 per row)
    for (int i = t; i < 64 * 14; i += 256) {
        int ci = i / 14, w4 = (i - ci * 14) * 4;
        float4 v = *(const float4*)(src + (size_t)ci * HW + w4);
        tile[ci][w4] = v.x; tile[ci][w4 + 1] = v.y;
        tile[ci][w4 + 2] = v.z; tile[ci][w4 + 3] = v.w;
    }
    __syncthreads();
    // abs-sum partials: ci = t&63, 4 w-groups of 14
    {
        int ci = t & 63, wg = t >> 6;
        float a = 0.f;
#pragma unroll
        for (int j = 0; j < 14; j++) a += fabsf(tile[ci][wg * 14 + j]);
        red2[t] = a;
    }
    __syncthreads();
    if (t < 64) {
        float tot = red2[t] + red2[t + 64] + red2[t + 128] + red2[t + 192];
        atomicAdd(&s[b * C_IN + cit * 64 + t], tot * (1.0f / (float)HW));
    }
    // write padded bf16: 4 ci per thread -> 8B stores, coalesced along ci
    for (int i = t; i < W_SZ * 16; i += 256) {
        int w = i >> 4, c4 = (i & 15) * 4;
        uint_t lo = (uint_t)f2bf(tile[c4][w])     | ((uint_t)f2bf(tile[c4 + 1][w]) << 16);
        uint_t hi = (uint_t)f2bf(tile[c4 + 2][w]) | ((uint_t)f2bf(tile[c4 + 3][w]) << 16);
        size_t dst = ((size_t)((b * HP + h + 1) * WP + (w + 1))) * C_IN + cit * 64 + c4;
        *(uint2*)&xbp[dst] = make_uint2(lo, hi);
    }
}

// ---------------------------------------------------------------------------
// Kernel 2: weights OIHW fp32 -> Wt[tap][co][ci] bf16; + BN constants
// ---------------------------------------------------------------------------
__global__ __launch_bounds__(256) void prep_w_kernel(const float* __restrict__ w,
                                                     const float* __restrict__ gamma,
                                                     const float* __restrict__ beta,
                                                     const float* __restrict__ mean,
                                                     const float* __restrict__ var,
                                                     ushort_t* __restrict__ Wt,
                                                     float* __restrict__ bninv,
                                                     float* __restrict__ bnadd) {
    int idx = blockIdx.x * 256 + threadIdx.x;
    if (idx < 9 * C_OUT * C_IN) {
        int tap = idx >> 16;
        int rem = idx & 65535;
        int co = rem >> 8, ci = rem & 255;
        Wt[idx] = f2bf(w[(size_t)(co * C_IN + ci) * 9 + tap]);
    }
    if (blockIdx.x == 0 && threadIdx.x < C_OUT) {
        int c = threadIdx.x;
        float inv = gamma[c] * rsqrtf(var[c] + BN_EPS);
        bninv[c] = inv;
        bnadd[c] = beta[c] - mean[c] * inv;
    }
}

// ---------------------------------------------------------------------------
// Kernel 3: gate = relu(s @ gw^T + gb); zero K smallest (tie: lower index),
// renormalize *C_OUT/sum -> tscale[b][co].
// ---------------------------------------------------------------------------
__global__ __launch_bounds__(256) void gate_kernel(const float* __restrict__ s,
                                                   const float* __restrict__ gw,
                                                   const float* __restrict__ gb,
                                                   float* __restrict__ tscale) {
    const int b = blockIdx.x, t = threadIdx.x;
    __shared__ float sh_s[C_IN], sh_g[C_OUT], red[256];
    sh_s[t] = s[b * C_IN + t];
    __syncthreads();
    float acc = gb[t];
    const float* wr = gw + (size_t)t * C_IN;
    for (int ci = 0; ci < C_IN; ci++) acc += sh_s[ci] * wr[ci];
    float g = fmaxf(acc, 0.f);
    sh_g[t] = g;
    __syncthreads();
    int cnt = 0;
    for (int j = 0; j < C_OUT; j++) {
        float gj = sh_g[j];
        cnt += (gj < g) || (gj == g && j < t);
    }
    float tv = (cnt >= K_ZERO) ? g : 0.f;
    red[t] = tv;
    __syncthreads();
    for (int off = 128; off > 0; off >>= 1) {
        if (t < off) red[t] += red[t + off];
        __syncthreads();
    }
    tscale[b * C_OUT + t] = tv * ((float)C_OUT / red[0]);
}

// ---------------------------------------------------------------------------
// Kernel 4: implicit-GEMM conv + BN + ReLU + channel scale (m97 structure)
// C[p][co] = sum_k Xcol[p][k] W[k][co], k=(tap,ci), K=2304, BK=64 (1 tap, 64 ci)
// tile 128x128, 4 waves x (4x4) 16x16x32 MFMAs; global_load_lds width=16;
// XOR chunk swizzle folded into the per-lane GLOBAL address (LDS dest must
// stay lane-sequential for global_load_lds).
// grid: (784, 2), block 256
// ---------------------------------------------------------------------------
__global__ __launch_bounds__(256) void conv_kernel(const ushort_t* __restrict__ xbp,
                                                   const ushort_t* __restrict__ Wt,
                                                   const float* __restrict__ bninv,
                                                   const float* __restrict__ bnadd,
                                                   const float* __restrict__ tscale,
                                                   float* __restrict__ out) {
    __shared__ __align__(16) ushort_t As[128 * 64];  // 16 KB, rows of 64 ci
    __shared__ __align__(16) ushort_t Bs[128 * 64];  // 16 KB
    const int t = threadIdx.x;
    const int bx = blockIdx.x;  // p tile (784)
    const int by = blockIdx.y;  // co tile (2)
    const int lane = t & 63;
    const int wv = t >> 6;
    const int waveM = wv >> 1, waveN = wv & 1;

    // ---- staging addresses (hoisted): LDS chunk q = i*256+t; row=q>>3=i*32+(t>>3),
    // stored col = t&7, global chunk col = (t&7) ^ (row&7)  (i*32 ≡ 0 mod 8).
    const int srow = t >> 3;
    const int gxor8 = ((t & 7) ^ (srow & 7)) * 8;  // element offset within 64-ci slice
    int arow[4], wrow[4];
#pragma unroll
    for (int i = 0; i < 4; i++) {
        int p = bx * 128 + i * 32 + srow;
        int b = p / HW;
        int r = p - b * HW;
        int hh = r / W_SZ, ww = r - hh * W_SZ;
        arow[i] = ((b * HP + hh + 1) * WP + (ww + 1)) * C_IN + gxor8;
        wrow[i] = (by * 128 + i * 32 + srow) * C_IN + gxor8;
    }
    ushort_t* ldsA = As + t * 8;  // + i*2048 elements per staging instr
    ushort_t* ldsB = Bs + t * 8;

    // ---- fragment LDS byte offsets (hoisted): row r, chunk c stored at c^(r&7)
    int aoff[2][4], boff[2][4];
#pragma unroll
    for (int ks = 0; ks < 2; ks++)
#pragma unroll
        for (int mt = 0; mt < 4; mt++) {
            int c = (lane >> 4) + ks * 4;
            int ra = waveM * 64 + mt * 16 + (lane & 15);
            aoff[ks][mt] = (ra * 8 + (c ^ (ra & 7))) * 16;
            int rb = waveN * 64 + mt * 16 + (lane & 15);
            boff[ks][mt] = (rb * 8 + (c ^ (rb & 7))) * 16;
        }

    f32x4 acc[4][4];
#pragma unroll
    for (int i = 0; i < 4; i++)
#pragma unroll
        for (int j = 0; j < 4; j++) acc[i][j] = (f32x4){0.f, 0.f, 0.f, 0.f};

    const char* Ab = (const char*)As;
    const char* Bb = (const char*)Bs;

    for (int tap = 0; tap < 9; tap++) {
        const int doff = ((tap / 3 - 1) * WP + (tap % 3 - 1)) * C_IN;
        const int woff = tap * (C_OUT * C_IN);
#pragma unroll
        for (int cq = 0; cq < 4; cq++) {
            const int ci0 = cq * 64;
#pragma unroll
            for (int i = 0; i < 4; i++) {
                load_lds16(xbp + arow[i] + doff + ci0, ldsA + i * 2048);
                load_lds16(Wt + wrow[i] + woff + ci0, ldsB + i * 2048);
            }
            __syncthreads();  // drains vmcnt -> LDS tiles complete
#pragma unroll
            for (int ks = 0; ks < 2; ks++) {
                bf16x8 af[4], bf[4];
#pragma unroll
                for (int mt = 0; mt < 4; mt++) af[mt] = *(const bf16x8*)(Ab + aoff[ks][mt]);
#pragma unroll
                for (int nt = 0; nt < 4; nt++) bf[nt] = *(const bf16x8*)(Bb + boff[ks][nt]);
#pragma unroll
                for (int mt = 0; mt < 4; mt++)
#pragma unroll
                    for (int nt = 0; nt < 4; nt++)
                        acc[mt][nt] = __builtin_amdgcn_mfma_f32_16x16x32_bf16(
                            af[mt], bf[nt], acc[mt][nt], 0, 0, 0);
            }
            __syncthreads();  // all waves done reading before next overwrite
        }
    }

    // epilogue: y = relu(acc*inv + add) * tscale[b][co]; out NCHW fp32.
    // C/D: co = lane&15 col, p = (lane>>4)*4 + reg; float4 along p (3136%4==0).
#pragma unroll
    for (int mt = 0; mt < 4; mt++) {
        int p0 = bx * 128 + waveM * 64 + mt * 16 + (lane >> 4) * 4;
        int b = p0 / HW;
        int hw = p0 - b * HW;
#pragma unroll
        for (int nt = 0; nt < 4; nt++) {
            int co = by * 128 + waveN * 64 + nt * 16 + (lane & 15);
            float inv = bninv[co], add = bnadd[co], tsc = tscale[b * C_OUT + co];
            float4 o;
            o.x = fmaxf(acc[mt][nt][0] * inv + add, 0.f) * tsc;
            o.y = fmaxf(acc[mt][nt][1] * inv + add, 0.f) * tsc;
            o.z = fmaxf(acc[mt][nt][2] * inv + add, 0.f) * tsc;
            o.w = fmaxf(acc[mt][nt][3] * inv + add, 0.f) * tsc;
            *(float4*)(out + (size_t)(b * C_OUT + co) * HW + hw) = o;
        }
    }
}

// ---------------------------------------------------------------------------
extern "C" void kernel_launch(void* const* d_in, const int* in_sizes, int n_in,
                              void* d_out, int out_size, void* d_ws, size_t ws_size,
                              hipStream_t stream) {
    const float* x      = (const float*)d_in[0];
    const float* conv_w = (const float*)d_in[1];
    const float* gate_w = (const float*)d_in[2];
    const float* gate_b = (const float*)d_in[3];
    const float* bn_g   = (const float*)d_in[4];
    const float* bn_b   = (const float*)d_in[5];
    const float* bn_m   = (const float*)d_in[6];
    const float* bn_v   = (const float*)d_in[7];
    float* out = (float*)d_out;

    // workspace layout (~56.4 MB)
    char* ws = (char*)d_ws;
    float*    s      = (float*)(ws + 0);          // 8192 f (atomic acc, zeroed)
    float*    tscale = (float*)(ws + 32768);      // 8192 f
    float*    bninv  = (float*)(ws + 65536);      // 256 f
    float*    bnadd  = (float*)(ws + 66560);      // 256 f
    ushort_t* Wt     = (ushort_t*)(ws + 67584);   // 589824 bf16 -> end 1247232
    ushort_t* xbp    = (ushort_t*)(ws + 1247232); // 32*58*58*256 bf16 = 55115776 B

    hipMemsetAsync(s, 0, 32768, stream);
    hipMemsetAsync(xbp, 0, (size_t)B_SZ * HP * WP * C_IN * 2, stream);
    prep_x_kernel<<<dim3(4, 56, 32), 256, 0, stream>>>(x, xbp, s);
    prep_w_kernel<<<2304, 256, 0, stream>>>(conv_w, bn_g, bn_b, bn_m, bn_v, Wt, bninv, bnadd);
    gate_kernel<<<32, 256, 0, stream>>>(s, gate_w, gate_b, tscale);
    conv_kernel<<<dim3(784, 2), 256, 0, stream>>>(xbp, Wt, bninv, bnadd, tscale, out);
}